// Round 7
// baseline (104.802 us; speedup 1.0000x reference)
//
#include <hip/hip_runtime.h>

#define FEAT 128
#define NPB 128            // nodes per bucket
#define NPB_SHIFT 7
#define SBITS 25           // low bits of packed edge = src id (N < 2^25)
#define SMASK ((1u << SBITS) - 1u)
#define NSCAT 256          // scatter blocks in K1 (= cells per bucket)
#define CAPB 64            // slots per (bucket, cell); mean fill ~8
#define CAPB_SHIFT 6
#define NGEMV 256          // gemv blocks in K1
#define NBMAX 1024         // persistent-kernel co-residency bound (4/CU x 256 CU)
#define TPB 256

// Agent-scope relaxed store: goes to memory-side LLC, bypasses (does not dirty) L2.
__device__ __forceinline__ void astore_f(float* p, float v) {
    __hip_atomic_store(p, v, __ATOMIC_RELAXED, __HIP_MEMORY_SCOPE_AGENT);
}

// Fence-free grid barrier (proven in R5). Relies on __syncthreads() draining vmcnt
// so prior agent-scope stores are complete before the arrival add.
__device__ __forceinline__ void gsync(int* bar, int target) {
    __syncthreads();
    if (threadIdx.x == 0) {
        __hip_atomic_fetch_add(bar, 1, __ATOMIC_RELAXED, __HIP_MEMORY_SCOPE_AGENT);
        while (__hip_atomic_load(bar, __ATOMIC_RELAXED, __HIP_MEMORY_SCOPE_AGENT) < target)
            __builtin_amdgcn_s_sleep(4);
    }
    __syncthreads();
}

// ---------------- K1: scatter (blocks 0..NSCAT-1) || z = x.w (rest) ----------------
// Plain cached writes; the K1->K2 dispatch boundary is the (only) full coherence flush.
__global__ void k1_scat_gemv(const float* __restrict__ x, const int* __restrict__ src,
                             const int* __restrict__ dst, const float* __restrict__ w,
                             int N, int E, int NB, int chunk,
                             unsigned* __restrict__ ebuf, unsigned char* __restrict__ cnt2,
                             float* __restrict__ z, int* __restrict__ bar) {
    const int b = blockIdx.x;
    const int t = threadIdx.x;
    if (b == 0 && t == 0) *bar = 0;          // reset barrier for K2 (flushed at kernel end)
    if (b < NSCAT) {
        __shared__ int h[NBMAX];
        const int k = b;
        int beg = k * chunk;
        int end = min(E, beg + chunk);
        for (int i = t; i < NB; i += TPB) h[i] = 0;
        __syncthreads();
        for (int e = beg + t; e < end; e += TPB) {
            int s = src[e], d = dst[e];
            int bk = d >> NPB_SHIFT;
            int l = atomicAdd(&h[bk], 1);                    // LDS atomic
            if (l < CAPB)                                    // ~never hit (Poisson(8) vs 64)
                ebuf[((size_t)(bk * NSCAT + k) << CAPB_SHIFT) + l] =
                    ((unsigned)(d & (NPB - 1)) << SBITS) | (unsigned)s;
        }
        __syncthreads();
        for (int i = t; i < NB; i += TPB)
            cnt2[(size_t)i * NSCAT + k] = (unsigned char)min(h[i], CAPB);
    } else {
        int gb  = b - NSCAT;
        int hw  = t >> 5;            // 8 half-waves per block
        int l32 = t & 31;
        float4 wv = ((const float4*)w)[l32];
        for (int node = gb * 8 + hw; node < N; node += NGEMV * 8) {
            float4 xv = ((const float4*)(x + (size_t)node * FEAT))[l32];
            float s = xv.x * wv.x + xv.y * wv.y + xv.z * wv.z + xv.w * wv.w;
            #pragma unroll
            for (int o = 16; o >= 1; o >>= 1) s += __shfl_xor(s, o, 64);  // stays in 32-group
            if (l32 == 0) z[node] = s;
        }
    }
}

// One hop phase: uout[d] = dinv[d]^2 (sum_{s->d} uin[s] + uin[d]); LAST writes (..+bias)^2.
// uin/dinv were agent-written in an earlier phase and are read with plain cached loads
// (first touch misses L2 -> fetches from the LLC coherence point; then L2-hot).
template <bool LAST>
__device__ __forceinline__ void hop_phase(const unsigned* __restrict__ ebuf,
                                          const unsigned char* __restrict__ cnt2,
                                          const float* __restrict__ dinv,
                                          const float* __restrict__ uin,
                                          float* __restrict__ uout,
                                          const float* __restrict__ bias,
                                          int N, int b, int t, float* acc) {
    if (t < NPB) acc[t] = 0.0f;
    __syncthreads();
    {
        int cnt = cnt2[(size_t)b * NSCAT + t];               // one cell per thread
        const unsigned* cell = ebuf + ((size_t)(b * NSCAT + t) << CAPB_SHIFT);
        for (int j = 0; j < cnt; ++j) {
            unsigned p = cell[j];
            atomicAdd(&acc[p >> SBITS], uin[p & SMASK]);     // LDS atomic, cached gather
        }
    }
    __syncthreads();
    if (t < NPB) {
        int node = (b << NPB_SHIFT) + t;
        if (node < N) {
            float d = dinv[node];
            float sum = acc[t] + uin[node];
            if (LAST) { float v = d * sum + bias[0]; uout[node] = v * v; }   // plain: kernel-end flush
            else      { astore_f(&uout[node], d * d * sum); }                // agent: pre-barrier publish
        }
    }
}

// ---------------- K2: persistent [deg+u0] -bar- hop1 -bar- hop2 -bar- hop3 ----------------
__global__ void __launch_bounds__(TPB, 4) k2_fused(
    const unsigned* __restrict__ ebuf, const unsigned char* __restrict__ cnt2,
    const float* __restrict__ z, const float* __restrict__ bias,
    float* __restrict__ dinv, float* __restrict__ u0, float* __restrict__ u1,
    float* __restrict__ u2, float* __restrict__ out, int* __restrict__ bar,
    int N, int NB)
{
    __shared__ int   cdeg[NPB];
    __shared__ float acc[NPB];
    const int b = blockIdx.x;
    const int t = threadIdx.x;

    // Phase 0: degree -> dinv, u0 = dinv * z  (ebuf/cnt2/z cached first-touch after K1)
    if (t < NPB) cdeg[t] = 0;
    __syncthreads();
    {
        int cnt = cnt2[(size_t)b * NSCAT + t];
        const unsigned* cell = ebuf + ((size_t)(b * NSCAT + t) << CAPB_SHIFT);
        for (int j = 0; j < cnt; ++j)
            atomicAdd(&cdeg[cell[j] >> SBITS], 1);
    }
    __syncthreads();
    if (t < NPB) {
        int node = (b << NPB_SHIFT) + t;
        if (node < N) {
            float dv = 1.0f / sqrtf(1.0f + (float)cdeg[t]);
            astore_f(&dinv[node], dv);
            astore_f(&u0[node], dv * z[node]);
        }
    }
    gsync(bar, NB);

    hop_phase<false>(ebuf, cnt2, dinv, u0, u1, bias, N, b, t, acc);
    gsync(bar, 2 * NB);
    hop_phase<false>(ebuf, cnt2, dinv, u1, u2, bias, N, b, t, acc);
    gsync(bar, 3 * NB);
    hop_phase<true >(ebuf, cnt2, dinv, u2, out, bias, N, b, t, acc);
}

// ---------------- fallback path (global atomics, proven correct) ----------------
__global__ void f_init_deg(float* __restrict__ deg, int N) {
    int i = blockIdx.x * blockDim.x + threadIdx.x;
    if (i < N) deg[i] = 1.0f;
}
__global__ void f_count_deg(const int* __restrict__ dst, float* __restrict__ deg, int E) {
    int e = blockIdx.x * blockDim.x + threadIdx.x;
    if (e < E) unsafeAtomicAdd(&deg[dst[e]], 1.0f);
}
__global__ void f_dot_dinv(const float* __restrict__ x, const float* __restrict__ w,
                           const float* __restrict__ deg, float* __restrict__ dinv,
                           float* __restrict__ z, int N) {
    int wid  = (blockIdx.x * blockDim.x + threadIdx.x) >> 6;
    int lane = threadIdx.x & 63;
    if (wid >= N) return;
    const float2* xr = reinterpret_cast<const float2*>(x + (size_t)wid * FEAT);
    const float2* wr = reinterpret_cast<const float2*>(w);
    float2 xv = xr[lane];
    float2 wv = wr[lane];
    float s = xv.x * wv.x + xv.y * wv.y;
    #pragma unroll
    for (int o = 32; o >= 1; o >>= 1) s += __shfl_xor(s, o, 64);
    if (lane == 0) { z[wid] = s; dinv[wid] = 1.0f / sqrtf(deg[wid]); }
}
__global__ void f_hop_self(const float* __restrict__ za, const float* __restrict__ dinv,
                           float* __restrict__ zb, int N) {
    int i = blockIdx.x * blockDim.x + threadIdx.x;
    if (i < N) { float d = dinv[i]; zb[i] = d * d * za[i]; }
}
__global__ void f_hop_edges(const int* __restrict__ src, const int* __restrict__ dst,
                            const float* __restrict__ za, const float* __restrict__ dinv,
                            float* __restrict__ zb, int E) {
    int e = blockIdx.x * blockDim.x + threadIdx.x;
    if (e < E) {
        int s = src[e], d = dst[e];
        unsafeAtomicAdd(&zb[d], dinv[s] * dinv[d] * za[s]);
    }
}
__global__ void f_final(const float* __restrict__ z, const float* __restrict__ bias,
                        float* __restrict__ out, int N) {
    int i = blockIdx.x * blockDim.x + threadIdx.x;
    if (i < N) { float v = z[i] + bias[0]; out[i] = v * v; }
}

// ---------------- launcher ----------------
extern "C" void kernel_launch(void* const* d_in, const int* in_sizes, int n_in,
                              void* d_out, int out_size, void* d_ws, size_t ws_size,
                              hipStream_t stream) {
    const float* x    = (const float*)d_in[0];
    const int*   ei   = (const int*)d_in[1];
    const float* w    = (const float*)d_in[2];
    const float* bias = (const float*)d_in[3];
    float*       out  = (float*)d_out;

    const int N = in_sizes[0] / FEAT;
    const int E = in_sizes[1] / 2;
    const int* src = ei;
    const int* dst = ei + E;

    const int NB = (N + NPB - 1) >> NPB_SHIFT;

    // ws layout: ebuf | z,dinv,u0,u1,u2 | bar (own line) | cnt2
    size_t ebuf_elems = (size_t)NB * NSCAT * CAPB;
    size_t off_z    = ebuf_elems * sizeof(unsigned);
    size_t off_bar  = (off_z + (size_t)5 * N * sizeof(float) + 255) & ~(size_t)255;
    size_t off_cnt2 = off_bar + 256;
    size_t need     = off_cnt2 + (size_t)NB * NSCAT + 256;

    bool fast = (NB <= NBMAX) && (N <= (1 << SBITS)) &&
                ((size_t)E * 4 <= (size_t)NB * NSCAT * CAPB) &&   // mean cell fill <= CAPB/4
                (ws_size >= need);

    if (fast) {
        unsigned*      ebuf = (unsigned*)d_ws;
        float*         z    = (float*)((char*)d_ws + off_z);
        float*         dinv = z + N;
        float*         u0   = dinv + N;
        float*         u1   = u0 + N;
        float*         u2   = u1 + N;
        int*           bar  = (int*)((char*)d_ws + off_bar);
        unsigned char* cnt2 = (unsigned char*)((char*)d_ws + off_cnt2);

        const int chunk = (E + NSCAT - 1) / NSCAT;

        k1_scat_gemv<<<NSCAT + NGEMV, TPB, 0, stream>>>(x, src, dst, w, N, E, NB, chunk,
                                                        ebuf, cnt2, z, bar);
        k2_fused<<<NB, TPB, 0, stream>>>(ebuf, cnt2, z, bias, dinv, u0, u1, u2, out, bar,
                                         N, NB);
    } else {
        float* deg  = (float*)d_ws;
        float* dinv = deg;
        float* z0   = deg + N;
        float* z1   = z0 + N;
        const int B = 256;
        const int gN = (N + B - 1) / B;
        const int gE = (E + B - 1) / B;
        const int gW = (N * 64 + B - 1) / B;
        f_init_deg<<<gN, B, 0, stream>>>(deg, N);
        f_count_deg<<<gE, B, 0, stream>>>(dst, deg, E);
        f_dot_dinv<<<gW, B, 0, stream>>>(x, w, deg, dinv, z0, N);
        f_hop_self<<<gN, B, 0, stream>>>(z0, dinv, z1, N);
        f_hop_edges<<<gE, B, 0, stream>>>(src, dst, z0, dinv, z1, E);
        f_hop_self<<<gN, B, 0, stream>>>(z1, dinv, z0, N);
        f_hop_edges<<<gE, B, 0, stream>>>(src, dst, z1, dinv, z0, E);
        f_hop_self<<<gN, B, 0, stream>>>(z0, dinv, z1, N);
        f_hop_edges<<<gE, B, 0, stream>>>(src, dst, z0, dinv, z1, E);
        f_final<<<gN, B, 0, stream>>>(z1, bias, out, N);
    }
}

// Round 8
// 80.277 us; speedup vs baseline: 1.3055x; 1.3055x over previous
//
#include <hip/hip_runtime.h>

#define FEAT 128
#define NPB 64             // nodes per bucket
#define NPB_SHIFT 6
#define SBITS 26           // low bits of packed edge = src id (N < 2^26)
#define SMASK ((1u << SBITS) - 1u)
#define NSCAT 256          // scatter blocks in K1 (= cells per bucket)
#define CAPB 32            // slots per (bucket, cell); mean fill ~4
#define CAPB_SHIFT 5
#define NGEMV 256          // gemv blocks in K1
#define NBMAX 1024         // persistent-kernel co-residency bound (4/CU x 256 CU)
#define TPB 256
#define FLAG_STRIDE 32     // ints; one release flag per 128-B line

__device__ __forceinline__ void astore_f(float* p, float v) {
    __hip_atomic_store(p, v, __ATOMIC_RELAXED, __HIP_MEMORY_SCOPE_AGENT);
}

// Grid barrier: central arrival counter (RMW only, "last" via fetch_add return)
// + per-block padded release flags (1 poller per line -> no contention).
__device__ __forceinline__ void gsync(int* bar, int* flags, int nb, int epoch) {
    __shared__ int lastblk;
    __syncthreads();                       // drains vmcnt: prior agent stores complete
    if (threadIdx.x == 0) {
        int old = __hip_atomic_fetch_add(bar, 1, __ATOMIC_RELAXED, __HIP_MEMORY_SCOPE_AGENT);
        lastblk = (old == epoch * nb - 1) ? 1 : 0;
    }
    __syncthreads();
    if (lastblk) {
        for (int i = threadIdx.x; i < nb; i += blockDim.x)
            __hip_atomic_store(&flags[i * FLAG_STRIDE], epoch,
                               __ATOMIC_RELAXED, __HIP_MEMORY_SCOPE_AGENT);
    } else if (threadIdx.x == 0) {
        while (__hip_atomic_load(&flags[blockIdx.x * FLAG_STRIDE],
                                 __ATOMIC_RELAXED, __HIP_MEMORY_SCOPE_AGENT) < epoch)
            __builtin_amdgcn_s_sleep(1);
    }
    __syncthreads();
}

// ---------------- K1: scatter (blocks 0..NSCAT-1) || z = x.w (rest) ----------------
__global__ void k1_scat_gemv(const float* __restrict__ x, const int* __restrict__ src,
                             const int* __restrict__ dst, const float* __restrict__ w,
                             int N, int E, int NB, int chunk,
                             unsigned* __restrict__ ebuf, unsigned char* __restrict__ cnt2,
                             float* __restrict__ z, int* __restrict__ bar,
                             int* __restrict__ flags) {
    const int b = blockIdx.x;
    const int t = threadIdx.x;
    if (b < NSCAT) {
        __shared__ int h[NBMAX];
        const int k = b;
        int beg = k * chunk;
        int end = min(E, beg + chunk);
        for (int i = t; i < NB; i += TPB) h[i] = 0;
        __syncthreads();
        for (int e = beg + t; e < end; e += TPB) {
            int s = src[e], d = dst[e];
            int bk = d >> NPB_SHIFT;
            int l = atomicAdd(&h[bk], 1);                    // LDS atomic
            if (l < CAPB)                                    // ~never (Poisson(4) vs 32)
                ebuf[((size_t)(bk * NSCAT + k) << CAPB_SHIFT) + l] =
                    ((unsigned)(d & (NPB - 1)) << SBITS) | (unsigned)s;
        }
        __syncthreads();
        for (int i = t; i < NB; i += TPB)
            cnt2[(size_t)i * NSCAT + k] = (unsigned char)min(h[i], CAPB);
    } else {
        if (b == NSCAT) {                  // reset barrier state (flushed at kernel end)
            if (t == 0) *bar = 0;
            for (int i = t; i < NB; i += TPB) flags[i * FLAG_STRIDE] = 0;
        }
        int gb  = b - NSCAT;
        int hw  = t >> 5;                  // 8 half-waves per block
        int l32 = t & 31;
        float4 wv = ((const float4*)w)[l32];
        for (int node = gb * 8 + hw; node < N; node += NGEMV * 8) {
            float4 xv = ((const float4*)(x + (size_t)node * FEAT))[l32];
            float s = xv.x * wv.x + xv.y * wv.y + xv.z * wv.z + xv.w * wv.w;
            #pragma unroll
            for (int o = 16; o >= 1; o >>= 1) s += __shfl_xor(s, o, 64);
            if (l32 == 0) z[node] = s;
        }
    }
}

// One hop: uout[d] = dinv[d]^2 (sum_{s->d} uin[s] + uin[d]); LAST writes (..+bias)^2.
template <bool LAST>
__device__ __forceinline__ void hop_phase(const unsigned* __restrict__ ebuf,
                                          const unsigned char* __restrict__ cnt2,
                                          const float* __restrict__ dinv,
                                          const float* __restrict__ uin,
                                          float* __restrict__ uout,
                                          const float* __restrict__ bias,
                                          int N, int b, int t, float* acc) {
    if (t < NPB) acc[t] = 0.0f;
    __syncthreads();
    {
        int cnt = cnt2[(size_t)b * NSCAT + t];               // one cell per thread
        const unsigned* cell = ebuf + ((size_t)(b * NSCAT + t) << CAPB_SHIFT);
        for (int j = 0; j < cnt; ++j) {
            unsigned p = cell[j];
            atomicAdd(&acc[p >> SBITS], uin[p & SMASK]);     // LDS atomic, cached gather
        }
    }
    __syncthreads();
    if (t < NPB) {
        int node = (b << NPB_SHIFT) + t;
        if (node < N) {
            float d = dinv[node];
            float sum = acc[t] + uin[node];
            if (LAST) { float v = d * sum + bias[0]; uout[node] = v * v; }  // plain: end flush
            else      { astore_f(&uout[node], d * d * sum); }               // agent publish
        }
    }
}

// ---------------- K2: persistent [deg+u0] -bar- hop1 -bar- hop2 -bar- hop3 ----------------
__global__ void __launch_bounds__(TPB, 4) k2_fused(
    const unsigned* __restrict__ ebuf, const unsigned char* __restrict__ cnt2,
    const float* __restrict__ z, const float* __restrict__ bias,
    float* __restrict__ dinv, float* __restrict__ u0, float* __restrict__ u1,
    float* __restrict__ u2, float* __restrict__ out, int* __restrict__ bar,
    int* __restrict__ flags, int N, int NB)
{
    __shared__ int   cdeg[NPB];
    __shared__ float acc[NPB];
    const int b = blockIdx.x;
    const int t = threadIdx.x;

    // Phase 0: degree -> dinv, u0 = dinv * z   (ebuf/cnt2/z coherent via K1 boundary)
    if (t < NPB) cdeg[t] = 0;
    __syncthreads();
    {
        int cnt = cnt2[(size_t)b * NSCAT + t];
        const unsigned* cell = ebuf + ((size_t)(b * NSCAT + t) << CAPB_SHIFT);
        for (int j = 0; j < cnt; ++j)
            atomicAdd(&cdeg[cell[j] >> SBITS], 1);
    }
    __syncthreads();
    if (t < NPB) {
        int node = (b << NPB_SHIFT) + t;
        if (node < N) {
            float dv = 1.0f / sqrtf(1.0f + (float)cdeg[t]);
            astore_f(&dinv[node], dv);
            astore_f(&u0[node], dv * z[node]);
        }
    }
    gsync(bar, flags, NB, 1);

    hop_phase<false>(ebuf, cnt2, dinv, u0, u1, bias, N, b, t, acc);
    gsync(bar, flags, NB, 2);
    hop_phase<false>(ebuf, cnt2, dinv, u1, u2, bias, N, b, t, acc);
    gsync(bar, flags, NB, 3);
    hop_phase<true >(ebuf, cnt2, dinv, u2, out, bias, N, b, t, acc);
}

// ---------------- fallback path (global atomics, proven correct) ----------------
__global__ void f_init_deg(float* __restrict__ deg, int N) {
    int i = blockIdx.x * blockDim.x + threadIdx.x;
    if (i < N) deg[i] = 1.0f;
}
__global__ void f_count_deg(const int* __restrict__ dst, float* __restrict__ deg, int E) {
    int e = blockIdx.x * blockDim.x + threadIdx.x;
    if (e < E) unsafeAtomicAdd(&deg[dst[e]], 1.0f);
}
__global__ void f_dot_dinv(const float* __restrict__ x, const float* __restrict__ w,
                           const float* __restrict__ deg, float* __restrict__ dinv,
                           float* __restrict__ z, int N) {
    int wid  = (blockIdx.x * blockDim.x + threadIdx.x) >> 6;
    int lane = threadIdx.x & 63;
    if (wid >= N) return;
    const float2* xr = reinterpret_cast<const float2*>(x + (size_t)wid * FEAT);
    const float2* wr = reinterpret_cast<const float2*>(w);
    float2 xv = xr[lane];
    float2 wv = wr[lane];
    float s = xv.x * wv.x + xv.y * wv.y;
    #pragma unroll
    for (int o = 32; o >= 1; o >>= 1) s += __shfl_xor(s, o, 64);
    if (lane == 0) { z[wid] = s; dinv[wid] = 1.0f / sqrtf(deg[wid]); }
}
__global__ void f_hop_self(const float* __restrict__ za, const float* __restrict__ dinv,
                           float* __restrict__ zb, int N) {
    int i = blockIdx.x * blockDim.x + threadIdx.x;
    if (i < N) { float d = dinv[i]; zb[i] = d * d * za[i]; }
}
__global__ void f_hop_edges(const int* __restrict__ src, const int* __restrict__ dst,
                            const float* __restrict__ za, const float* __restrict__ dinv,
                            float* __restrict__ zb, int E) {
    int e = blockIdx.x * blockDim.x + threadIdx.x;
    if (e < E) {
        int s = src[e], d = dst[e];
        unsafeAtomicAdd(&zb[d], dinv[s] * dinv[d] * za[s]);
    }
}
__global__ void f_final(const float* __restrict__ z, const float* __restrict__ bias,
                        float* __restrict__ out, int N) {
    int i = blockIdx.x * blockDim.x + threadIdx.x;
    if (i < N) { float v = z[i] + bias[0]; out[i] = v * v; }
}

// ---------------- launcher ----------------
extern "C" void kernel_launch(void* const* d_in, const int* in_sizes, int n_in,
                              void* d_out, int out_size, void* d_ws, size_t ws_size,
                              hipStream_t stream) {
    const float* x    = (const float*)d_in[0];
    const int*   ei   = (const int*)d_in[1];
    const float* w    = (const float*)d_in[2];
    const float* bias = (const float*)d_in[3];
    float*       out  = (float*)d_out;

    const int N = in_sizes[0] / FEAT;
    const int E = in_sizes[1] / 2;
    const int* src = ei;
    const int* dst = ei + E;

    const int NB = (N + NPB - 1) >> NPB_SHIFT;

    // ws layout: ebuf | z,dinv,u0,u1,u2 | bar line | flags | cnt2
    size_t ebuf_elems = (size_t)NB * NSCAT * CAPB;
    size_t off_z     = ebuf_elems * sizeof(unsigned);
    size_t off_bar   = (off_z + (size_t)5 * N * sizeof(float) + 255) & ~(size_t)255;
    size_t off_flags = off_bar + 256;
    size_t off_cnt2  = off_flags + (size_t)NB * FLAG_STRIDE * sizeof(int);
    size_t need      = off_cnt2 + (size_t)NB * NSCAT + 256;

    bool fast = (NB <= NBMAX) && (N <= (1 << SBITS)) &&
                ((size_t)E * 4 <= (size_t)NB * NSCAT * CAPB) &&   // mean cell fill <= CAPB/4
                (ws_size >= need);

    if (fast) {
        unsigned*      ebuf  = (unsigned*)d_ws;
        float*         z     = (float*)((char*)d_ws + off_z);
        float*         dinv  = z + N;
        float*         u0    = dinv + N;
        float*         u1    = u0 + N;
        float*         u2    = u1 + N;
        int*           bar   = (int*)((char*)d_ws + off_bar);
        int*           flags = (int*)((char*)d_ws + off_flags);
        unsigned char* cnt2  = (unsigned char*)((char*)d_ws + off_cnt2);

        const int chunk = (E + NSCAT - 1) / NSCAT;

        k1_scat_gemv<<<NSCAT + NGEMV, TPB, 0, stream>>>(x, src, dst, w, N, E, NB, chunk,
                                                        ebuf, cnt2, z, bar, flags);
        k2_fused<<<NB, TPB, 0, stream>>>(ebuf, cnt2, z, bias, dinv, u0, u1, u2, out, bar,
                                         flags, N, NB);
    } else {
        float* deg  = (float*)d_ws;
        float* dinv = deg;
        float* z0   = deg + N;
        float* z1   = z0 + N;
        const int B = 256;
        const int gN = (N + B - 1) / B;
        const int gE = (E + B - 1) / B;
        const int gW = (N * 64 + B - 1) / B;
        f_init_deg<<<gN, B, 0, stream>>>(deg, N);
        f_count_deg<<<gE, B, 0, stream>>>(dst, deg, E);
        f_dot_dinv<<<gW, B, 0, stream>>>(x, w, deg, dinv, z0, N);
        f_hop_self<<<gN, B, 0, stream>>>(z0, dinv, z1, N);
        f_hop_edges<<<gE, B, 0, stream>>>(src, dst, z0, dinv, z1, E);
        f_hop_self<<<gN, B, 0, stream>>>(z1, dinv, z0, N);
        f_hop_edges<<<gE, B, 0, stream>>>(src, dst, z1, dinv, z0, E);
        f_hop_self<<<gN, B, 0, stream>>>(z0, dinv, z1, N);
        f_hop_edges<<<gE, B, 0, stream>>>(src, dst, z0, dinv, z1, E);
        f_final<<<gN, B, 0, stream>>>(z1, bias, out, N);
    }
}

// Round 9
// 60.769 us; speedup vs baseline: 1.7246x; 1.3210x over previous
//
#include <hip/hip_runtime.h>

#define FEAT 128
#define NPB 64             // nodes per bucket
#define NPB_SHIFT 6
#define SBITS 26           // low bits of packed edge = src id (N < 2^26)
#define SMASK ((1u << SBITS) - 1u)
#define NSCAT 256          // scatter blocks in K1 (= cells per bucket)
#define CAPB 32            // slots per (bucket, cell); mean fill ~4
#define CAPB_SHIFT 5
#define NGEMV 512          // gemv blocks in K1
#define NBMAX 1024         // persistent-kernel co-residency bound (4/CU x 256 CU)
#define TPB 256
#define LINE 32            // ints per 128-B line (padding unit)
#define GSH 5              // arrival-tree group shift (32 blocks/group)
#define GS (1 << GSH)

__device__ __forceinline__ void astore_f(float* p, float v) {
    __hip_atomic_store(p, v, __ATOMIC_RELAXED, __HIP_MEMORY_SCOPE_AGENT);
}
__device__ __forceinline__ int afadd(int* p) {
    return __hip_atomic_fetch_add(p, 1, __ATOMIC_RELAXED, __HIP_MEMORY_SCOPE_AGENT);
}

// Grid barrier, two-level arrival tree + per-block padded release flags.
// Arrival: RMW on group counter (own line); group-last RMWs root; root-last releases.
// No thread ever polls a shared line (release flags are 1 poller/line).
__device__ __forceinline__ void gsync(int* gcnt, int* root, int* flags,
                                      int nb, int ng, int epoch) {
    __shared__ int lastblk;
    __syncthreads();                       // drains vmcnt: prior agent stores complete
    if (threadIdx.x == 0) {
        lastblk = 0;
        int g = blockIdx.x >> GSH;
        int gsize = min(GS, nb - (g << GSH));
        int old = afadd(&gcnt[g * LINE]);
        if (old == epoch * gsize - 1) {            // last in group this epoch
            int rold = afadd(root);
            if (rold == epoch * ng - 1) lastblk = 1;   // last in grid this epoch
        }
    }
    __syncthreads();
    if (lastblk) {
        for (int i = threadIdx.x; i < nb; i += TPB)
            __hip_atomic_store(&flags[i * LINE], epoch,
                               __ATOMIC_RELAXED, __HIP_MEMORY_SCOPE_AGENT);
    } else if (threadIdx.x == 0) {
        while (__hip_atomic_load(&flags[blockIdx.x * LINE],
                                 __ATOMIC_RELAXED, __HIP_MEMORY_SCOPE_AGENT) < epoch)
            __builtin_amdgcn_s_sleep(1);
    }
    __syncthreads();
}

// ---------------- K1: scatter (blocks 0..NSCAT-1) || z = x.w (rest) ----------------
__global__ void k1_scat_gemv(const float* __restrict__ x, const int* __restrict__ src,
                             const int* __restrict__ dst, const float* __restrict__ w,
                             int N, int E, int NB, int NG, int chunk,
                             unsigned* __restrict__ ebuf, unsigned char* __restrict__ cnt2,
                             float* __restrict__ z, int* __restrict__ gcnt,
                             int* __restrict__ root, int* __restrict__ flags) {
    const int b = blockIdx.x;
    const int t = threadIdx.x;
    if (b < NSCAT) {
        __shared__ int h[NBMAX];
        const int k = b;
        int beg = k * chunk;
        int end = min(E, beg + chunk);
        for (int i = t; i < NB; i += TPB) h[i] = 0;
        __syncthreads();
        for (int e = beg + t; e < end; e += TPB) {
            int s = src[e], d = dst[e];
            int bk = d >> NPB_SHIFT;
            int l = atomicAdd(&h[bk], 1);                    // LDS atomic
            if (l < CAPB)                                    // ~never (Poisson(4) vs 32)
                ebuf[((size_t)(bk * NSCAT + k) << CAPB_SHIFT) + l] =
                    ((unsigned)(d & (NPB - 1)) << SBITS) | (unsigned)s;
        }
        __syncthreads();
        for (int i = t; i < NB; i += TPB)
            cnt2[(size_t)i * NSCAT + k] = (unsigned char)min(h[i], CAPB);
    } else {
        if (b == NSCAT) {                  // reset barrier state (flushed at kernel end)
            if (t == 0) *root = 0;
            for (int i = t; i < NG; i += TPB) gcnt[i * LINE] = 0;
            for (int i = t; i < NB; i += TPB) flags[i * LINE] = 0;
        }
        int gb  = b - NSCAT;
        int hw  = t >> 5;                  // 8 half-waves per block
        int l32 = t & 31;
        float4 wv = ((const float4*)w)[l32];
        for (int node = gb * 8 + hw; node < N; node += NGEMV * 8) {
            float4 xv = ((const float4*)(x + (size_t)node * FEAT))[l32];
            float s = xv.x * wv.x + xv.y * wv.y + xv.z * wv.z + xv.w * wv.w;
            #pragma unroll
            for (int o = 16; o >= 1; o >>= 1) s += __shfl_xor(s, o, 64);
            if (l32 == 0) z[node] = s;
        }
    }
}

// One hop: uout[d] = dinv[d]^2 (sum_{s->d} uin[s] + uin[d]); LAST writes (..+bias)^2.
template <bool LAST>
__device__ __forceinline__ void hop_phase(const unsigned* __restrict__ ebuf,
                                          const unsigned char* __restrict__ cnt2,
                                          const float* __restrict__ dinv,
                                          const float* __restrict__ uin,
                                          float* __restrict__ uout,
                                          const float* __restrict__ bias,
                                          int N, int b, int t, float* acc) {
    if (t < NPB) acc[t] = 0.0f;
    __syncthreads();
    {
        int cnt = cnt2[(size_t)b * NSCAT + t];               // one cell per thread
        const unsigned* cell = ebuf + ((size_t)(b * NSCAT + t) << CAPB_SHIFT);
        for (int j = 0; j < cnt; ++j) {
            unsigned p = cell[j];
            atomicAdd(&acc[p >> SBITS], uin[p & SMASK]);     // LDS atomic, cached gather
        }
    }
    __syncthreads();
    if (t < NPB) {
        int node = (b << NPB_SHIFT) + t;
        if (node < N) {
            float d = dinv[node];
            float sum = acc[t] + uin[node];
            if (LAST) { float v = d * sum + bias[0]; uout[node] = v * v; }  // plain: end flush
            else      { astore_f(&uout[node], d * d * sum); }               // agent publish
        }
    }
}

// ---------------- K2: persistent [deg+u0] -bar- hop1 -bar- hop2 -bar- hop3 ----------------
__global__ void __launch_bounds__(TPB, 4) k2_fused(
    const unsigned* __restrict__ ebuf, const unsigned char* __restrict__ cnt2,
    const float* __restrict__ z, const float* __restrict__ bias,
    float* __restrict__ dinv, float* __restrict__ u0, float* __restrict__ u1,
    float* __restrict__ u2, float* __restrict__ out, int* __restrict__ gcnt,
    int* __restrict__ root, int* __restrict__ flags, int N, int NB, int NG)
{
    __shared__ int   cdeg[NPB];
    __shared__ float acc[NPB];
    const int b = blockIdx.x;
    const int t = threadIdx.x;

    // Phase 0: degree -> dinv, u0 = dinv * z   (ebuf/cnt2/z coherent via K1 boundary)
    if (t < NPB) cdeg[t] = 0;
    __syncthreads();
    {
        int cnt = cnt2[(size_t)b * NSCAT + t];
        const unsigned* cell = ebuf + ((size_t)(b * NSCAT + t) << CAPB_SHIFT);
        for (int j = 0; j < cnt; ++j)
            atomicAdd(&cdeg[cell[j] >> SBITS], 1);
    }
    __syncthreads();
    if (t < NPB) {
        int node = (b << NPB_SHIFT) + t;
        if (node < N) {
            float dv = 1.0f / sqrtf(1.0f + (float)cdeg[t]);
            astore_f(&dinv[node], dv);
            astore_f(&u0[node], dv * z[node]);
        }
    }
    gsync(gcnt, root, flags, NB, NG, 1);

    hop_phase<false>(ebuf, cnt2, dinv, u0, u1, bias, N, b, t, acc);
    gsync(gcnt, root, flags, NB, NG, 2);
    hop_phase<false>(ebuf, cnt2, dinv, u1, u2, bias, N, b, t, acc);
    gsync(gcnt, root, flags, NB, NG, 3);
    hop_phase<true >(ebuf, cnt2, dinv, u2, out, bias, N, b, t, acc);
}

// ---------------- fallback path (global atomics, proven correct) ----------------
__global__ void f_init_deg(float* __restrict__ deg, int N) {
    int i = blockIdx.x * blockDim.x + threadIdx.x;
    if (i < N) deg[i] = 1.0f;
}
__global__ void f_count_deg(const int* __restrict__ dst, float* __restrict__ deg, int E) {
    int e = blockIdx.x * blockDim.x + threadIdx.x;
    if (e < E) unsafeAtomicAdd(&deg[dst[e]], 1.0f);
}
__global__ void f_dot_dinv(const float* __restrict__ x, const float* __restrict__ w,
                           const float* __restrict__ deg, float* __restrict__ dinv,
                           float* __restrict__ z, int N) {
    int wid  = (blockIdx.x * blockDim.x + threadIdx.x) >> 6;
    int lane = threadIdx.x & 63;
    if (wid >= N) return;
    const float2* xr = reinterpret_cast<const float2*>(x + (size_t)wid * FEAT);
    const float2* wr = reinterpret_cast<const float2*>(w);
    float2 xv = xr[lane];
    float2 wv = wr[lane];
    float s = xv.x * wv.x + xv.y * wv.y;
    #pragma unroll
    for (int o = 32; o >= 1; o >>= 1) s += __shfl_xor(s, o, 64);
    if (lane == 0) { z[wid] = s; dinv[wid] = 1.0f / sqrtf(deg[wid]); }
}
__global__ void f_hop_self(const float* __restrict__ za, const float* __restrict__ dinv,
                           float* __restrict__ zb, int N) {
    int i = blockIdx.x * blockDim.x + threadIdx.x;
    if (i < N) { float d = dinv[i]; zb[i] = d * d * za[i]; }
}
__global__ void f_hop_edges(const int* __restrict__ src, const int* __restrict__ dst,
                            const float* __restrict__ za, const float* __restrict__ dinv,
                            float* __restrict__ zb, int E) {
    int e = blockIdx.x * blockDim.x + threadIdx.x;
    if (e < E) {
        int s = src[e], d = dst[e];
        unsafeAtomicAdd(&zb[d], dinv[s] * dinv[d] * za[s]);
    }
}
__global__ void f_final(const float* __restrict__ z, const float* __restrict__ bias,
                        float* __restrict__ out, int N) {
    int i = blockIdx.x * blockDim.x + threadIdx.x;
    if (i < N) { float v = z[i] + bias[0]; out[i] = v * v; }
}

// ---------------- launcher ----------------
extern "C" void kernel_launch(void* const* d_in, const int* in_sizes, int n_in,
                              void* d_out, int out_size, void* d_ws, size_t ws_size,
                              hipStream_t stream) {
    const float* x    = (const float*)d_in[0];
    const int*   ei   = (const int*)d_in[1];
    const float* w    = (const float*)d_in[2];
    const float* bias = (const float*)d_in[3];
    float*       out  = (float*)d_out;

    const int N = in_sizes[0] / FEAT;
    const int E = in_sizes[1] / 2;
    const int* src = ei;
    const int* dst = ei + E;

    const int NB = (N + NPB - 1) >> NPB_SHIFT;
    const int NG = (NB + GS - 1) >> GSH;

    // ws layout: ebuf | z,dinv,u0,u1,u2 | root line | gcnt | flags | cnt2
    size_t ebuf_elems = (size_t)NB * NSCAT * CAPB;
    size_t off_z     = ebuf_elems * sizeof(unsigned);
    size_t off_root  = (off_z + (size_t)5 * N * sizeof(float) + 255) & ~(size_t)255;
    size_t off_gcnt  = off_root + 256;
    size_t off_flags = off_gcnt + (size_t)NG * LINE * sizeof(int);
    size_t off_cnt2  = off_flags + (size_t)NB * LINE * sizeof(int);
    size_t need      = off_cnt2 + (size_t)NB * NSCAT + 256;

    bool fast = (NB <= NBMAX) && (N <= (1 << SBITS)) &&
                ((size_t)E * 4 <= (size_t)NB * NSCAT * CAPB) &&   // mean cell fill <= CAPB/4
                (ws_size >= need);

    if (fast) {
        unsigned*      ebuf  = (unsigned*)d_ws;
        float*         z     = (float*)((char*)d_ws + off_z);
        float*         dinv  = z + N;
        float*         u0    = dinv + N;
        float*         u1    = u0 + N;
        float*         u2    = u1 + N;
        int*           root  = (int*)((char*)d_ws + off_root);
        int*           gcnt  = (int*)((char*)d_ws + off_gcnt);
        int*           flags = (int*)((char*)d_ws + off_flags);
        unsigned char* cnt2  = (unsigned char*)((char*)d_ws + off_cnt2);

        const int chunk = (E + NSCAT - 1) / NSCAT;

        k1_scat_gemv<<<NSCAT + NGEMV, TPB, 0, stream>>>(x, src, dst, w, N, E, NB, NG,
                                                        chunk, ebuf, cnt2, z,
                                                        gcnt, root, flags);
        k2_fused<<<NB, TPB, 0, stream>>>(ebuf, cnt2, z, bias, dinv, u0, u1, u2, out,
                                         gcnt, root, flags, N, NB, NG);
    } else {
        float* deg  = (float*)d_ws;
        float* dinv = deg;
        float* z0   = deg + N;
        float* z1   = z0 + N;
        const int B = 256;
        const int gN = (N + B - 1) / B;
        const int gE = (E + B - 1) / B;
        const int gW = (N * 64 + B - 1) / B;
        f_init_deg<<<gN, B, 0, stream>>>(deg, N);
        f_count_deg<<<gE, B, 0, stream>>>(dst, deg, E);
        f_dot_dinv<<<gW, B, 0, stream>>>(x, w, deg, dinv, z0, N);
        f_hop_self<<<gN, B, 0, stream>>>(z0, dinv, z1, N);
        f_hop_edges<<<gE, B, 0, stream>>>(src, dst, z0, dinv, z1, E);
        f_hop_self<<<gN, B, 0, stream>>>(z1, dinv, z0, N);
        f_hop_edges<<<gE, B, 0, stream>>>(src, dst, z1, dinv, z0, E);
        f_hop_self<<<gN, B, 0, stream>>>(z0, dinv, z1, N);
        f_hop_edges<<<gE, B, 0, stream>>>(src, dst, z0, dinv, z1, E);
        f_final<<<gN, B, 0, stream>>>(z1, bias, out, N);
    }
}

// Round 10
// 59.601 us; speedup vs baseline: 1.7584x; 1.0196x over previous
//
#include <hip/hip_runtime.h>

#define FEAT 128
#define NPB 64             // nodes per bucket
#define NPB_SHIFT 6
#define SBITS 26           // low bits of packed edge = src id (N < 2^26)
#define SMASK ((1u << SBITS) - 1u)
#define NSCAT 256          // scatter blocks in K1 (= cells per bucket)
#define CAPB 32            // slots per (bucket, cell); mean fill ~4
#define CAPB_SHIFT 5
#define NGEMV 512          // gemv blocks in K1
#define NBMAX 1024         // persistent-kernel co-residency bound (4/CU x 256 CU)
#define TPB 256
#define LINE 32            // ints per 128-B line (release-flag padding)

__device__ __forceinline__ void astore_f(float* p, float v) {
    __hip_atomic_store(p, v, __ATOMIC_RELAXED, __HIP_MEMORY_SCOPE_AGENT);
}
__device__ __forceinline__ void astore_i(int* p, int v) {
    __hip_atomic_store(p, v, __ATOMIC_RELAXED, __HIP_MEMORY_SCOPE_AGENT);
}
__device__ __forceinline__ int aload_i(const int* p) {
    return __hip_atomic_load(p, __ATOMIC_RELAXED, __HIP_MEMORY_SCOPE_AGENT);
}

// Grid barrier: store-arrival (dense arr, 1 relaxed agent store per block) +
// coordinator scan (block 0, 256 threads) + padded per-block release flags
// (1 poller per line). No same-line RMWs anywhere.
__device__ __forceinline__ void gsync(int* arr, int* flags, int nb, int epoch) {
    __syncthreads();                       // drains vmcnt: prior agent stores complete
    if (blockIdx.x == 0) {
        for (;;) {
            int ok = 1;
            for (int i = 1 + threadIdx.x; i < nb; i += TPB)
                if (aload_i(&arr[i]) < epoch) { ok = 0; break; }
            if (__syncthreads_and(ok)) break;
            __builtin_amdgcn_s_sleep(1);
        }
        for (int i = threadIdx.x; i < nb; i += TPB)
            astore_i(&flags[i * LINE], epoch);
    } else {
        if (threadIdx.x == 0) {
            astore_i(&arr[blockIdx.x], epoch);
            while (aload_i(&flags[blockIdx.x * LINE]) < epoch)
                __builtin_amdgcn_s_sleep(1);
        }
    }
    __syncthreads();
}

// ---------------- K1: scatter (blocks 0..NSCAT-1) || z = x.w (rest) ----------------
__global__ void k1_scat_gemv(const float* __restrict__ x, const int* __restrict__ src,
                             const int* __restrict__ dst, const float* __restrict__ w,
                             int N, int E, int NB, int chunk,
                             unsigned* __restrict__ ebuf, unsigned char* __restrict__ cnt2,
                             float* __restrict__ z, int* __restrict__ arr,
                             int* __restrict__ flags) {
    const int b = blockIdx.x;
    const int t = threadIdx.x;
    if (b < NSCAT) {
        __shared__ int h[NBMAX];
        const int k = b;
        int beg = k * chunk;
        int end = min(E, beg + chunk);
        for (int i = t; i < NB; i += TPB) h[i] = 0;
        __syncthreads();
        for (int e = beg + t; e < end; e += TPB) {
            int s = src[e], d = dst[e];
            int bk = d >> NPB_SHIFT;
            int l = atomicAdd(&h[bk], 1);                    // LDS atomic
            if (l < CAPB)                                    // ~never (Poisson(4) vs 32)
                ebuf[((size_t)(bk * NSCAT + k) << CAPB_SHIFT) + l] =
                    ((unsigned)(d & (NPB - 1)) << SBITS) | (unsigned)s;
        }
        __syncthreads();
        for (int i = t; i < NB; i += TPB)
            cnt2[(size_t)i * NSCAT + k] = (unsigned char)min(h[i], CAPB);
    } else {
        if (b == NSCAT) {                  // reset barrier state (flushed at kernel end)
            for (int i = t; i < NB; i += TPB) arr[i] = 0;
            for (int i = t; i < NB; i += TPB) flags[i * LINE] = 0;
        }
        int gb  = b - NSCAT;
        int hw  = t >> 5;                  // 8 half-waves per block
        int l32 = t & 31;
        float4 wv = ((const float4*)w)[l32];
        for (int node = gb * 8 + hw; node < N; node += NGEMV * 8) {
            float4 xv = ((const float4*)(x + (size_t)node * FEAT))[l32];
            float s = xv.x * wv.x + xv.y * wv.y + xv.z * wv.z + xv.w * wv.w;
            #pragma unroll
            for (int o = 16; o >= 1; o >>= 1) s += __shfl_xor(s, o, 64);
            if (l32 == 0) z[node] = s;
        }
    }
}

// Gather one cell's edges into LDS acc; first 8 unrolled (independent loads
// issued together -> latencies overlap), tail scalar.
__device__ __forceinline__ void gather_cell(const unsigned* __restrict__ cell, int cnt,
                                            const float* __restrict__ uin, float* acc) {
    uint4 c0 = ((const uint4*)cell)[0];
    uint4 c1 = ((const uint4*)cell)[1];
    unsigned pk0 = c0.x, pk1 = c0.y, pk2 = c0.z, pk3 = c0.w;
    unsigned pk4 = c1.x, pk5 = c1.y, pk6 = c1.z, pk7 = c1.w;
    if (0 < cnt) atomicAdd(&acc[pk0 >> SBITS], uin[pk0 & SMASK]);
    if (1 < cnt) atomicAdd(&acc[pk1 >> SBITS], uin[pk1 & SMASK]);
    if (2 < cnt) atomicAdd(&acc[pk2 >> SBITS], uin[pk2 & SMASK]);
    if (3 < cnt) atomicAdd(&acc[pk3 >> SBITS], uin[pk3 & SMASK]);
    if (4 < cnt) atomicAdd(&acc[pk4 >> SBITS], uin[pk4 & SMASK]);
    if (5 < cnt) atomicAdd(&acc[pk5 >> SBITS], uin[pk5 & SMASK]);
    if (6 < cnt) atomicAdd(&acc[pk6 >> SBITS], uin[pk6 & SMASK]);
    if (7 < cnt) atomicAdd(&acc[pk7 >> SBITS], uin[pk7 & SMASK]);
    for (int j = 8; j < cnt; ++j) {
        unsigned p = cell[j];
        atomicAdd(&acc[p >> SBITS], uin[p & SMASK]);
    }
}

// One hop: uout[d] = dinv[d]^2 (sum_{s->d} uin[s] + uin[d]); LAST writes (..+bias)^2.
template <bool LAST>
__device__ __forceinline__ void hop_phase(const unsigned* __restrict__ ebuf,
                                          const unsigned char* __restrict__ cnt2,
                                          const float* __restrict__ dinv,
                                          const float* __restrict__ uin,
                                          float* __restrict__ uout,
                                          const float* __restrict__ bias,
                                          int N, int b, int t, float* acc) {
    if (t < NPB) acc[t] = 0.0f;
    __syncthreads();
    {
        int cnt = cnt2[(size_t)b * NSCAT + t];               // one cell per thread
        const unsigned* cell = ebuf + ((size_t)(b * NSCAT + t) << CAPB_SHIFT);
        gather_cell(cell, cnt, uin, acc);
    }
    __syncthreads();
    if (t < NPB) {
        int node = (b << NPB_SHIFT) + t;
        if (node < N) {
            float d = dinv[node];
            float sum = acc[t] + uin[node];
            if (LAST) { float v = d * sum + bias[0]; uout[node] = v * v; }  // plain: end flush
            else      { astore_f(&uout[node], d * d * sum); }               // agent publish
        }
    }
}

// ---------------- K2: persistent [deg+u0] -bar- hop1 -bar- hop2 -bar- hop3 ----------------
__global__ void __launch_bounds__(TPB, 4) k2_fused(
    const unsigned* __restrict__ ebuf, const unsigned char* __restrict__ cnt2,
    const float* __restrict__ z, const float* __restrict__ bias,
    float* __restrict__ dinv, float* __restrict__ u0, float* __restrict__ u1,
    float* __restrict__ u2, float* __restrict__ out, int* __restrict__ arr,
    int* __restrict__ flags, int N, int NB)
{
    __shared__ int   cdeg[NPB];
    __shared__ float acc[NPB];
    const int b = blockIdx.x;
    const int t = threadIdx.x;

    // Phase 0: degree -> dinv, u0 = dinv * z   (ebuf/cnt2/z coherent via K1 boundary)
    if (t < NPB) cdeg[t] = 0;
    __syncthreads();
    {
        int cnt = cnt2[(size_t)b * NSCAT + t];
        const unsigned* cell = ebuf + ((size_t)(b * NSCAT + t) << CAPB_SHIFT);
        uint4 c0 = ((const uint4*)cell)[0];
        uint4 c1 = ((const uint4*)cell)[1];
        unsigned pk[8] = {c0.x, c0.y, c0.z, c0.w, c1.x, c1.y, c1.z, c1.w};
        #pragma unroll
        for (int k = 0; k < 8; ++k)
            if (k < cnt) atomicAdd(&cdeg[pk[k] >> SBITS], 1);
        for (int j = 8; j < cnt; ++j)
            atomicAdd(&cdeg[cell[j] >> SBITS], 1);
    }
    __syncthreads();
    if (t < NPB) {
        int node = (b << NPB_SHIFT) + t;
        if (node < N) {
            float dv = 1.0f / sqrtf(1.0f + (float)cdeg[t]);
            astore_f(&dinv[node], dv);
            astore_f(&u0[node], dv * z[node]);
        }
    }
    gsync(arr, flags, NB, 1);

    hop_phase<false>(ebuf, cnt2, dinv, u0, u1, bias, N, b, t, acc);
    gsync(arr, flags, NB, 2);
    hop_phase<false>(ebuf, cnt2, dinv, u1, u2, bias, N, b, t, acc);
    gsync(arr, flags, NB, 3);
    hop_phase<true >(ebuf, cnt2, dinv, u2, out, bias, N, b, t, acc);
}

// ---------------- fallback path (global atomics, proven correct) ----------------
__global__ void f_init_deg(float* __restrict__ deg, int N) {
    int i = blockIdx.x * blockDim.x + threadIdx.x;
    if (i < N) deg[i] = 1.0f;
}
__global__ void f_count_deg(const int* __restrict__ dst, float* __restrict__ deg, int E) {
    int e = blockIdx.x * blockDim.x + threadIdx.x;
    if (e < E) unsafeAtomicAdd(&deg[dst[e]], 1.0f);
}
__global__ void f_dot_dinv(const float* __restrict__ x, const float* __restrict__ w,
                           const float* __restrict__ deg, float* __restrict__ dinv,
                           float* __restrict__ z, int N) {
    int wid  = (blockIdx.x * blockDim.x + threadIdx.x) >> 6;
    int lane = threadIdx.x & 63;
    if (wid >= N) return;
    const float2* xr = reinterpret_cast<const float2*>(x + (size_t)wid * FEAT);
    const float2* wr = reinterpret_cast<const float2*>(w);
    float2 xv = xr[lane];
    float2 wv = wr[lane];
    float s = xv.x * wv.x + xv.y * wv.y;
    #pragma unroll
    for (int o = 32; o >= 1; o >>= 1) s += __shfl_xor(s, o, 64);
    if (lane == 0) { z[wid] = s; dinv[wid] = 1.0f / sqrtf(deg[wid]); }
}
__global__ void f_hop_self(const float* __restrict__ za, const float* __restrict__ dinv,
                           float* __restrict__ zb, int N) {
    int i = blockIdx.x * blockDim.x + threadIdx.x;
    if (i < N) { float d = dinv[i]; zb[i] = d * d * za[i]; }
}
__global__ void f_hop_edges(const int* __restrict__ src, const int* __restrict__ dst,
                            const float* __restrict__ za, const float* __restrict__ dinv,
                            float* __restrict__ zb, int E) {
    int e = blockIdx.x * blockDim.x + threadIdx.x;
    if (e < E) {
        int s = src[e], d = dst[e];
        unsafeAtomicAdd(&zb[d], dinv[s] * dinv[d] * za[s]);
    }
}
__global__ void f_final(const float* __restrict__ z, const float* __restrict__ bias,
                        float* __restrict__ out, int N) {
    int i = blockIdx.x * blockDim.x + threadIdx.x;
    if (i < N) { float v = z[i] + bias[0]; out[i] = v * v; }
}

// ---------------- launcher ----------------
extern "C" void kernel_launch(void* const* d_in, const int* in_sizes, int n_in,
                              void* d_out, int out_size, void* d_ws, size_t ws_size,
                              hipStream_t stream) {
    const float* x    = (const float*)d_in[0];
    const int*   ei   = (const int*)d_in[1];
    const float* w    = (const float*)d_in[2];
    const float* bias = (const float*)d_in[3];
    float*       out  = (float*)d_out;

    const int N = in_sizes[0] / FEAT;
    const int E = in_sizes[1] / 2;
    const int* src = ei;
    const int* dst = ei + E;

    const int NB = (N + NPB - 1) >> NPB_SHIFT;

    // ws layout: ebuf | z,dinv,u0,u1,u2 | arr | flags | cnt2
    size_t ebuf_elems = (size_t)NB * NSCAT * CAPB;
    size_t off_z     = ebuf_elems * sizeof(unsigned);
    size_t off_arr   = (off_z + (size_t)5 * N * sizeof(float) + 255) & ~(size_t)255;
    size_t off_flags = (off_arr + (size_t)NB * sizeof(int) + 255) & ~(size_t)255;
    size_t off_cnt2  = off_flags + (size_t)NB * LINE * sizeof(int);
    size_t need      = off_cnt2 + (size_t)NB * NSCAT + 256;

    bool fast = (NB <= NBMAX) && (N <= (1 << SBITS)) &&
                ((size_t)E * 4 <= (size_t)NB * NSCAT * CAPB) &&   // mean cell fill <= CAPB/4
                (ws_size >= need);

    if (fast) {
        unsigned*      ebuf  = (unsigned*)d_ws;
        float*         z     = (float*)((char*)d_ws + off_z);
        float*         dinv  = z + N;
        float*         u0    = dinv + N;
        float*         u1    = u0 + N;
        float*         u2    = u1 + N;
        int*           arr   = (int*)((char*)d_ws + off_arr);
        int*           flags = (int*)((char*)d_ws + off_flags);
        unsigned char* cnt2  = (unsigned char*)((char*)d_ws + off_cnt2);

        const int chunk = (E + NSCAT - 1) / NSCAT;

        k1_scat_gemv<<<NSCAT + NGEMV, TPB, 0, stream>>>(x, src, dst, w, N, E, NB,
                                                        chunk, ebuf, cnt2, z,
                                                        arr, flags);
        k2_fused<<<NB, TPB, 0, stream>>>(ebuf, cnt2, z, bias, dinv, u0, u1, u2, out,
                                         arr, flags, N, NB);
    } else {
        float* deg  = (float*)d_ws;
        float* dinv = deg;
        float* z0   = deg + N;
        float* z1   = z0 + N;
        const int B = 256;
        const int gN = (N + B - 1) / B;
        const int gE = (E + B - 1) / B;
        const int gW = (N * 64 + B - 1) / B;
        f_init_deg<<<gN, B, 0, stream>>>(deg, N);
        f_count_deg<<<gE, B, 0, stream>>>(dst, deg, E);
        f_dot_dinv<<<gW, B, 0, stream>>>(x, w, deg, dinv, z0, N);
        f_hop_self<<<gN, B, 0, stream>>>(z0, dinv, z1, N);
        f_hop_edges<<<gE, B, 0, stream>>>(src, dst, z0, dinv, z1, E);
        f_hop_self<<<gN, B, 0, stream>>>(z1, dinv, z0, N);
        f_hop_edges<<<gE, B, 0, stream>>>(src, dst, z1, dinv, z0, E);
        f_hop_self<<<gN, B, 0, stream>>>(z0, dinv, z1, N);
        f_hop_edges<<<gE, B, 0, stream>>>(src, dst, z0, dinv, z1, E);
        f_final<<<gN, B, 0, stream>>>(z1, bias, out, N);
    }
}

// Round 11
// 53.240 us; speedup vs baseline: 1.9685x; 1.1195x over previous
//
#include <hip/hip_runtime.h>

#define FEAT 128
#define NPB 98             // nodes per bucket (d/98 via compiler magic-mul)
#define SBITS 25           // low bits of packed edge = src id (N < 2^25)
#define SMASK ((1u << SBITS) - 1u)
#define NSCAT 256          // scatter blocks in K1 (= cells per bucket)
#define CAPB 32            // slots per (bucket, cell); mean fill ~6
#define CAPB_SHIFT 5
#define CAP2 4096          // dense per-bucket edge capacity (mean ~1566)
#define CAP2_SHIFT 12
#define NGEMV 256          // gemv blocks in K1
#define TPB 256
#define LINE 32            // ints per 128-B line (flag padding)
#define NBHIST 512

__device__ __forceinline__ void astore_f(float* p, float v) {
    __hip_atomic_store(p, v, __ATOMIC_RELAXED, __HIP_MEMORY_SCOPE_AGENT);
}
__device__ __forceinline__ void astore_i(int* p, int v) {
    __hip_atomic_store(p, v, __ATOMIC_RELAXED, __HIP_MEMORY_SCOPE_AGENT);
}
__device__ __forceinline__ int aload_i(const int* p) {
    return __hip_atomic_load(p, __ATOMIC_RELAXED, __HIP_MEMORY_SCOPE_AGENT);
}

// Worker side of the barrier: one arrival store + poll own padded flag.
__device__ __forceinline__ void wbar(int* arr, int* flags, int b, int ep) {
    __syncthreads();                      // drains vmcnt: agent stores complete
    if (threadIdx.x == 0) {
        astore_i(&arr[b], ep);
        while (aload_i(&flags[b * LINE]) < ep) __builtin_amdgcn_s_sleep(1);
    }
    __syncthreads();
}

// ---------------- K1: scatter (blocks 0..NSCAT-1) || z = x.w (rest) ----------------
__global__ void k1_scat_gemv(const float* __restrict__ x, const int* __restrict__ src,
                             const int* __restrict__ dst, const float* __restrict__ w,
                             int N, int E, int NB, int chunk,
                             unsigned* __restrict__ ebuf, unsigned char* __restrict__ cnt2,
                             float* __restrict__ z) {
    const int b = blockIdx.x;
    const int t = threadIdx.x;
    if (b < NSCAT) {
        __shared__ int h[NBHIST];
        for (int i = t; i < NB; i += TPB) h[i] = 0;
        __syncthreads();
        int beg = b * chunk;
        int end = min(E, beg + chunk);
        for (int e = beg + t; e < end; e += TPB) {
            int s = src[e], d = dst[e];
            int bk  = (int)((unsigned)d / NPB);          // magic-mul division
            int loc = d - bk * NPB;
            int l = atomicAdd(&h[bk], 1);                // LDS atomic
            if (l < CAPB)                                // ~never (Poisson(6) vs 32)
                ebuf[((size_t)(bk * NSCAT + b) << CAPB_SHIFT) + l] =
                    ((unsigned)loc << SBITS) | (unsigned)s;
        }
        __syncthreads();
        for (int i = t; i < NB; i += TPB)
            cnt2[(size_t)i * NSCAT + b] = (unsigned char)min(h[i], CAPB);
    } else {
        int gb  = b - NSCAT;
        int hw  = t >> 5;                  // 8 half-waves per block
        int l32 = t & 31;
        float4 wv = ((const float4*)w)[l32];
        for (int node = gb * 8 + hw; node < N; node += NGEMV * 8) {
            float4 xv = ((const float4*)(x + (size_t)node * FEAT))[l32];
            float s = xv.x * wv.x + xv.y * wv.y + xv.z * wv.z + xv.w * wv.w;
            #pragma unroll
            for (int o = 16; o >= 1; o >>= 1) s += __shfl_xor(s, o, 64);
            if (l32 == 0) z[node] = s;
        }
    }
}

// ---------------- K2: persistent, balanced grid NB+1 (=2 blocks/CU) ----------------
// P1{deg+u0+compact} -B1- hop1 -B2- hop2 -B3- hop3(out).  Block NB = coordinator.
__global__ void __launch_bounds__(TPB, 2) k2_fused(
    const unsigned* __restrict__ ebuf, const unsigned char* __restrict__ cnt2,
    const float* __restrict__ z, const float* __restrict__ bias,
    unsigned* __restrict__ ebuf2,
    float* __restrict__ u0, float* __restrict__ u1, float* __restrict__ u2,
    float* __restrict__ out, int* __restrict__ arr, int* __restrict__ flags,
    int N, int NB)
{
    const int b = blockIdx.x;
    const int t = threadIdx.x;

    if (b == NB) {
        // ---- coordinator: scan arrivals, fan out releases; no phase work ----
        for (int ep = 1; ep <= 3; ++ep) {
            for (;;) {
                int ok = 1;
                for (int i = t; i < NB; i += TPB)
                    if (aload_i(&arr[i]) < ep) { ok = 0; break; }
                if (__syncthreads_and(ok)) break;
                __builtin_amdgcn_s_sleep(2);
            }
            for (int i = t; i < NB; i += TPB)
                astore_i(&flags[i * LINE], ep);
        }
        return;
    }

    __shared__ float uown[NPB], dinvL[NPB], acc[NPB];
    __shared__ int   degL[NPB];
    __shared__ int   pref[TPB];
    __shared__ int   cntB_s;
    const int base = b * NPB;
    const int nn   = min(NPB, N - base);        // nodes in this bucket

    // ---- P1: cells -> deg histogram + dense compaction; u0 = dinv * z ----
    if (t < NPB) degL[t] = 0;
    __syncthreads();
    int cnt = cnt2[(size_t)b * NSCAT + t];
    pref[t] = cnt;
    __syncthreads();
    #pragma unroll
    for (int off = 1; off < TPB; off <<= 1) {    // Hillis-Steele inclusive scan
        int v = (t >= off) ? pref[t - off] : 0;
        __syncthreads();
        pref[t] += v;
        __syncthreads();
    }
    int mypos = pref[t] - cnt;                   // exclusive prefix
    if (t == TPB - 1) cntB_s = min(pref[t], CAP2);
    {
        const unsigned* cell = ebuf + ((size_t)(b * NSCAT + t) << CAPB_SHIFT);
        unsigned* dst2 = ebuf2 + ((size_t)b << CAP2_SHIFT);
        #pragma unroll 4
        for (int j = 0; j < cnt; ++j) {
            unsigned p = cell[j];
            atomicAdd(&degL[p >> SBITS], 1);     // LDS atomic
            int pos = mypos + j;
            if (pos < CAP2) dst2[pos] = p;       // plain store: own-block reads only
        }
    }
    __syncthreads();
    if (t < nn) {
        float dv = 1.0f / sqrtf(1.0f + (float)degL[t]);
        dinvL[t] = dv;
        float u = dv * z[base + t];
        uown[t] = u;
        astore_f(&u0[base + t], u);              // agent publish for remote gathers
    }
    wbar(arr, flags, b, 1);

    const unsigned* dst2 = ebuf2 + ((size_t)b << CAP2_SHIFT);
    const int cntB = cntB_s;

    // ---- hop1: gather u0 -> u1 ----
    if (t < NPB) acc[t] = 0.0f;
    __syncthreads();
    for (int j = t; j < cntB; j += TPB) {
        unsigned p = dst2[j];                    // L2-dirty hit (own lines)
        atomicAdd(&acc[p >> SBITS], u0[p & SMASK]);
    }
    __syncthreads();
    if (t < nn) {
        float dv = dinvL[t];
        float nu = dv * dv * (acc[t] + uown[t]);
        uown[t] = nu;
        astore_f(&u1[base + t], nu);
    }
    wbar(arr, flags, b, 2);

    // ---- hop2: gather u1 -> u2 ----
    if (t < NPB) acc[t] = 0.0f;
    __syncthreads();
    for (int j = t; j < cntB; j += TPB) {
        unsigned p = dst2[j];
        atomicAdd(&acc[p >> SBITS], u1[p & SMASK]);
    }
    __syncthreads();
    if (t < nn) {
        float dv = dinvL[t];
        float nu = dv * dv * (acc[t] + uown[t]);
        uown[t] = nu;
        astore_f(&u2[base + t], nu);
    }
    wbar(arr, flags, b, 3);

    // ---- hop3: gather u2 -> out = (dinv*sum + bias)^2 ----
    if (t < NPB) acc[t] = 0.0f;
    __syncthreads();
    for (int j = t; j < cntB; j += TPB) {
        unsigned p = dst2[j];
        atomicAdd(&acc[p >> SBITS], u2[p & SMASK]);
    }
    __syncthreads();
    if (t < nn) {
        float dv = dinvL[t];
        float v = dv * (acc[t] + uown[t]) + bias[0];
        out[base + t] = v * v;                   // plain: kernel-end flush
    }
    // reset barrier state for the next graph replay (safe: coordinator is done)
    if (t == 0) { astore_i(&arr[b], 0); astore_i(&flags[b * LINE], 0); }
}

// ---------------- fallback path (global atomics, proven correct) ----------------
__global__ void f_init_deg(float* __restrict__ deg, int N) {
    int i = blockIdx.x * blockDim.x + threadIdx.x;
    if (i < N) deg[i] = 1.0f;
}
__global__ void f_count_deg(const int* __restrict__ dst, float* __restrict__ deg, int E) {
    int e = blockIdx.x * blockDim.x + threadIdx.x;
    if (e < E) unsafeAtomicAdd(&deg[dst[e]], 1.0f);
}
__global__ void f_dot_dinv(const float* __restrict__ x, const float* __restrict__ w,
                           const float* __restrict__ deg, float* __restrict__ dinv,
                           float* __restrict__ z, int N) {
    int wid  = (blockIdx.x * blockDim.x + threadIdx.x) >> 6;
    int lane = threadIdx.x & 63;
    if (wid >= N) return;
    const float2* xr = reinterpret_cast<const float2*>(x + (size_t)wid * FEAT);
    const float2* wr = reinterpret_cast<const float2*>(w);
    float2 xv = xr[lane];
    float2 wv = wr[lane];
    float s = xv.x * wv.x + xv.y * wv.y;
    #pragma unroll
    for (int o = 32; o >= 1; o >>= 1) s += __shfl_xor(s, o, 64);
    if (lane == 0) { z[wid] = s; dinv[wid] = 1.0f / sqrtf(deg[wid]); }
}
__global__ void f_hop_self(const float* __restrict__ za, const float* __restrict__ dinv,
                           float* __restrict__ zb, int N) {
    int i = blockIdx.x * blockDim.x + threadIdx.x;
    if (i < N) { float d = dinv[i]; zb[i] = d * d * za[i]; }
}
__global__ void f_hop_edges(const int* __restrict__ src, const int* __restrict__ dst,
                            const float* __restrict__ za, const float* __restrict__ dinv,
                            float* __restrict__ zb, int E) {
    int e = blockIdx.x * blockDim.x + threadIdx.x;
    if (e < E) {
        int s = src[e], d = dst[e];
        unsafeAtomicAdd(&zb[d], dinv[s] * dinv[d] * za[s]);
    }
}
__global__ void f_final(const float* __restrict__ z, const float* __restrict__ bias,
                        float* __restrict__ out, int N) {
    int i = blockIdx.x * blockDim.x + threadIdx.x;
    if (i < N) { float v = z[i] + bias[0]; out[i] = v * v; }
}

// ---------------- launcher ----------------
extern "C" void kernel_launch(void* const* d_in, const int* in_sizes, int n_in,
                              void* d_out, int out_size, void* d_ws, size_t ws_size,
                              hipStream_t stream) {
    const float* x    = (const float*)d_in[0];
    const int*   ei   = (const int*)d_in[1];
    const float* w    = (const float*)d_in[2];
    const float* bias = (const float*)d_in[3];
    float*       out  = (float*)d_out;

    const int N = in_sizes[0] / FEAT;
    const int E = in_sizes[1] / 2;
    const int* src = ei;
    const int* dst = ei + E;

    const int NB = (N + NPB - 1) / NPB;

    // ws layout: ebuf | ebuf2 | z,u0,u1,u2 | arr | flags | cnt2
    size_t ebuf_b  = (size_t)NB * NSCAT * CAPB * sizeof(unsigned);
    size_t ebuf2_b = (size_t)NB * CAP2 * sizeof(unsigned);
    size_t off_e2    = ebuf_b;
    size_t off_z     = off_e2 + ebuf2_b;
    size_t off_arr   = (off_z + (size_t)4 * N * sizeof(float) + 255) & ~(size_t)255;
    size_t off_flags = (off_arr + (size_t)NB * sizeof(int) + 255) & ~(size_t)255;
    size_t off_cnt2  = off_flags + (size_t)NB * LINE * sizeof(int);
    size_t need      = off_cnt2 + (size_t)NB * NSCAT + 256;

    // co-residency: launch_bounds(256,2) -> 2 blocks/CU -> capacity 512 >= NB+1
    bool fast = (NB + 1 <= 512) && (N <= (1 << SBITS)) &&
                ((size_t)E <= (size_t)8 * NB * NSCAT) &&     // cell mean <= CAPB/4
                ((size_t)E * 2 <= (size_t)NB * CAP2) &&      // bucket mean <= CAP2/2
                (ws_size >= need);

    if (fast) {
        unsigned*      ebuf  = (unsigned*)d_ws;
        unsigned*      ebuf2 = (unsigned*)((char*)d_ws + off_e2);
        float*         z     = (float*)((char*)d_ws + off_z);
        float*         u0    = z + N;
        float*         u1    = u0 + N;
        float*         u2    = u1 + N;
        int*           arr   = (int*)((char*)d_ws + off_arr);
        int*           flags = (int*)((char*)d_ws + off_flags);
        unsigned char* cnt2  = (unsigned char*)((char*)d_ws + off_cnt2);

        const int chunk = (E + NSCAT - 1) / NSCAT;

        k1_scat_gemv<<<NSCAT + NGEMV, TPB, 0, stream>>>(x, src, dst, w, N, E, NB,
                                                        chunk, ebuf, cnt2, z);
        k2_fused<<<NB + 1, TPB, 0, stream>>>(ebuf, cnt2, z, bias, ebuf2,
                                             u0, u1, u2, out, arr, flags, N, NB);
    } else {
        float* deg  = (float*)d_ws;
        float* dinv = deg;
        float* z0   = deg + N;
        float* z1   = z0 + N;
        const int B = 256;
        const int gN = (N + B - 1) / B;
        const int gE = (E + B - 1) / B;
        const int gW = (N * 64 + B - 1) / B;
        f_init_deg<<<gN, B, 0, stream>>>(deg, N);
        f_count_deg<<<gE, B, 0, stream>>>(dst, deg, E);
        f_dot_dinv<<<gW, B, 0, stream>>>(x, w, deg, dinv, z0, N);
        f_hop_self<<<gN, B, 0, stream>>>(z0, dinv, z1, N);
        f_hop_edges<<<gE, B, 0, stream>>>(src, dst, z0, dinv, z1, E);
        f_hop_self<<<gN, B, 0, stream>>>(z1, dinv, z0, N);
        f_hop_edges<<<gE, B, 0, stream>>>(src, dst, z1, dinv, z0, E);
        f_hop_self<<<gN, B, 0, stream>>>(z0, dinv, z1, N);
        f_hop_edges<<<gE, B, 0, stream>>>(src, dst, z0, dinv, z1, E);
        f_final<<<gN, B, 0, stream>>>(z1, bias, out, N);
    }
}

// Round 12
// 51.309 us; speedup vs baseline: 2.0426x; 1.0376x over previous
//
#include <hip/hip_runtime.h>

#define FEAT 128
#define NPB 98             // nodes per bucket (d/98 via compiler magic-mul)
#define SBITS 25           // low bits of packed edge = src id (N < 2^25)
#define SMASK ((1u << SBITS) - 1u)
#define NSCAT 256          // scatter blocks in K1 (= cells per bucket)
#define CAPB 32            // slots per (bucket, cell); mean fill ~6
#define CAPB_SHIFT 5
#define CAP2 4096          // dense per-bucket edge capacity (mean ~1566)
#define CAP2_SHIFT 12
#define NGEMV 256          // gemv blocks in K1
#define TPB 256
#define LINE 32            // ints per 128-B line (padding unit)
#define GSH 4              // 16 blocks per barrier group
#define GS (1 << GSH)
#define NBHIST 512

__device__ __forceinline__ void astore_f(float* p, float v) {
    __hip_atomic_store(p, v, __ATOMIC_RELAXED, __HIP_MEMORY_SCOPE_AGENT);
}
__device__ __forceinline__ void astore_i(int* p, int v) {
    __hip_atomic_store(p, v, __ATOMIC_RELAXED, __HIP_MEMORY_SCOPE_AGENT);
}
__device__ __forceinline__ int aload_i(const int* p) {
    return __hip_atomic_load(p, __ATOMIC_RELAXED, __HIP_MEMORY_SCOPE_AGENT);
}

// Decentralized 2-level grid barrier. Arrival: fetch_add on per-group padded
// counter (<=16 serialized RMWs, groups parallel); group-last (return value,
// monotonic epochs) stores gflag[g]=ep. Detect: every block's threads t<ngrp
// poll gflag[t] in parallel; no coordinator, no release fan-out.
__device__ __forceinline__ void gbar(int* gcnt, int* gflag, int nb, int ngrp, int ep) {
    __syncthreads();                       // drains vmcnt: prior agent stores complete
    if (threadIdx.x == 0) {
        int g = blockIdx.x >> GSH;
        int gsize = min(GS, nb - (g << GSH));
        int old = __hip_atomic_fetch_add(&gcnt[g * LINE], 1,
                                         __ATOMIC_RELAXED, __HIP_MEMORY_SCOPE_AGENT);
        if (old == ep * gsize - 1)
            astore_i(&gflag[g * LINE], ep);
    }
    for (;;) {
        int ok = 1;
        if (threadIdx.x < ngrp)
            ok = (aload_i(&gflag[threadIdx.x * LINE]) >= ep);
        if (__syncthreads_and(ok)) break;
        __builtin_amdgcn_s_sleep(2);
    }
}

// ---------------- K1: scatter (blocks 0..NSCAT-1) || z = x.w (rest) ----------------
__global__ void k1_scat_gemv(const float* __restrict__ x, const int* __restrict__ src,
                             const int* __restrict__ dst, const float* __restrict__ w,
                             int N, int E, int NB, int NGRP, int chunk,
                             unsigned* __restrict__ ebuf, unsigned char* __restrict__ cnt2,
                             float* __restrict__ z, int* __restrict__ gcnt,
                             int* __restrict__ gflag) {
    const int b = blockIdx.x;
    const int t = threadIdx.x;
    if (b < NSCAT) {
        if (b == 0 && t < LINE * 2) {      // reset barrier state (2*NGRP <= 64 lines)
            if (t < NGRP) { gcnt[t * LINE] = 0; gflag[t * LINE] = 0; }
        }
        __shared__ int h[NBHIST];
        for (int i = t; i < NB; i += TPB) h[i] = 0;
        __syncthreads();
        int beg = b * chunk;
        int end = min(E, beg + chunk);
        for (int e = beg + t; e < end; e += TPB) {
            int s = src[e], d = dst[e];
            int bk  = (int)((unsigned)d / NPB);          // magic-mul division
            int loc = d - bk * NPB;
            int l = atomicAdd(&h[bk], 1);                // LDS atomic
            if (l < CAPB)                                // ~never (Poisson(6) vs 32)
                ebuf[((size_t)(bk * NSCAT + b) << CAPB_SHIFT) + l] =
                    ((unsigned)loc << SBITS) | (unsigned)s;
        }
        __syncthreads();
        for (int i = t; i < NB; i += TPB)
            cnt2[(size_t)i * NSCAT + b] = (unsigned char)min(h[i], CAPB);
    } else {
        int gb  = b - NSCAT;
        int hw  = t >> 5;                  // 8 half-waves per block
        int l32 = t & 31;
        float4 wv = ((const float4*)w)[l32];
        for (int node = gb * 8 + hw; node < N; node += NGEMV * 8) {
            float4 xv = ((const float4*)(x + (size_t)node * FEAT))[l32];
            float s = xv.x * wv.x + xv.y * wv.y + xv.z * wv.z + xv.w * wv.w;
            #pragma unroll
            for (int o = 16; o >= 1; o >>= 1) s += __shfl_xor(s, o, 64);
            if (l32 == 0) z[node] = s;
        }
    }
}

// ---------------- K2: persistent, grid NB (<=2 blocks/CU, balanced) ----------------
// P1{deg+u0+compact} -B1- hop1 -B2- hop2 -B3- hop3(out). Decentralized barrier.
__global__ void __launch_bounds__(TPB, 2) k2_fused(
    const unsigned* __restrict__ ebuf, const unsigned char* __restrict__ cnt2,
    const float* __restrict__ z, const float* __restrict__ bias,
    unsigned* __restrict__ ebuf2,
    float* __restrict__ u0, float* __restrict__ u1, float* __restrict__ u2,
    float* __restrict__ out, int* __restrict__ gcnt, int* __restrict__ gflag,
    int N, int NB, int NGRP)
{
    const int b = blockIdx.x;
    const int t = threadIdx.x;

    __shared__ float uown[NPB], dinvL[NPB], acc[NPB];
    __shared__ int   degL[NPB];
    __shared__ int   pref[TPB];
    __shared__ int   cntB_s;
    const int base = b * NPB;
    const int nn   = min(NPB, N - base);        // nodes in this bucket

    // ---- P1: cells -> deg histogram + dense compaction; u0 = dinv * z ----
    if (t < NPB) degL[t] = 0;
    __syncthreads();
    int cnt = cnt2[(size_t)b * NSCAT + t];
    pref[t] = cnt;
    __syncthreads();
    #pragma unroll
    for (int off = 1; off < TPB; off <<= 1) {    // Hillis-Steele inclusive scan
        int v = (t >= off) ? pref[t - off] : 0;
        __syncthreads();
        pref[t] += v;
        __syncthreads();
    }
    int mypos = pref[t] - cnt;                   // exclusive prefix
    if (t == TPB - 1) cntB_s = min(pref[t], CAP2);
    {
        const unsigned* cell = ebuf + ((size_t)(b * NSCAT + t) << CAPB_SHIFT);
        unsigned* dst2 = ebuf2 + ((size_t)b << CAP2_SHIFT);
        #pragma unroll 4
        for (int j = 0; j < cnt; ++j) {
            unsigned p = cell[j];
            atomicAdd(&degL[p >> SBITS], 1);     // LDS atomic
            int pos = mypos + j;
            if (pos < CAP2) dst2[pos] = p;       // plain store: own-block reads only
        }
    }
    __syncthreads();
    if (t < nn) {
        float dv = 1.0f / sqrtf(1.0f + (float)degL[t]);
        dinvL[t] = dv;
        float u = dv * z[base + t];
        uown[t] = u;
        astore_f(&u0[base + t], u);              // agent publish for remote gathers
    }
    gbar(gcnt, gflag, NB, NGRP, 1);

    const unsigned* dst2 = ebuf2 + ((size_t)b << CAP2_SHIFT);
    const int cntB = cntB_s;

    // ---- hop1: gather u0 -> u1 (uint4 idx loads -> 4 independent gathers) ----
    if (t < NPB) acc[t] = 0.0f;
    __syncthreads();
    for (int j = t * 4; j < cntB; j += TPB * 4) {
        uint4 q = *(const uint4*)(dst2 + j);
        atomicAdd(&acc[q.x >> SBITS], u0[q.x & SMASK]);
        if (j + 1 < cntB) atomicAdd(&acc[q.y >> SBITS], u0[q.y & SMASK]);
        if (j + 2 < cntB) atomicAdd(&acc[q.z >> SBITS], u0[q.z & SMASK]);
        if (j + 3 < cntB) atomicAdd(&acc[q.w >> SBITS], u0[q.w & SMASK]);
    }
    __syncthreads();
    if (t < nn) {
        float dv = dinvL[t];
        float nu = dv * dv * (acc[t] + uown[t]);
        uown[t] = nu;
        astore_f(&u1[base + t], nu);
    }
    gbar(gcnt, gflag, NB, NGRP, 2);

    // ---- hop2: gather u1 -> u2 ----
    if (t < NPB) acc[t] = 0.0f;
    __syncthreads();
    for (int j = t * 4; j < cntB; j += TPB * 4) {
        uint4 q = *(const uint4*)(dst2 + j);
        atomicAdd(&acc[q.x >> SBITS], u1[q.x & SMASK]);
        if (j + 1 < cntB) atomicAdd(&acc[q.y >> SBITS], u1[q.y & SMASK]);
        if (j + 2 < cntB) atomicAdd(&acc[q.z >> SBITS], u1[q.z & SMASK]);
        if (j + 3 < cntB) atomicAdd(&acc[q.w >> SBITS], u1[q.w & SMASK]);
    }
    __syncthreads();
    if (t < nn) {
        float dv = dinvL[t];
        float nu = dv * dv * (acc[t] + uown[t]);
        uown[t] = nu;
        astore_f(&u2[base + t], nu);
    }
    gbar(gcnt, gflag, NB, NGRP, 3);

    // ---- hop3: gather u2 -> out = (dinv*sum + bias)^2 ----
    if (t < NPB) acc[t] = 0.0f;
    __syncthreads();
    for (int j = t * 4; j < cntB; j += TPB * 4) {
        uint4 q = *(const uint4*)(dst2 + j);
        atomicAdd(&acc[q.x >> SBITS], u2[q.x & SMASK]);
        if (j + 1 < cntB) atomicAdd(&acc[q.y >> SBITS], u2[q.y & SMASK]);
        if (j + 2 < cntB) atomicAdd(&acc[q.z >> SBITS], u2[q.z & SMASK]);
        if (j + 3 < cntB) atomicAdd(&acc[q.w >> SBITS], u2[q.w & SMASK]);
    }
    __syncthreads();
    if (t < nn) {
        float dv = dinvL[t];
        float v = dv * (acc[t] + uown[t]) + bias[0];
        out[base + t] = v * v;                   // plain: kernel-end flush
    }
}

// ---------------- fallback path (global atomics, proven correct) ----------------
__global__ void f_init_deg(float* __restrict__ deg, int N) {
    int i = blockIdx.x * blockDim.x + threadIdx.x;
    if (i < N) deg[i] = 1.0f;
}
__global__ void f_count_deg(const int* __restrict__ dst, float* __restrict__ deg, int E) {
    int e = blockIdx.x * blockDim.x + threadIdx.x;
    if (e < E) unsafeAtomicAdd(&deg[dst[e]], 1.0f);
}
__global__ void f_dot_dinv(const float* __restrict__ x, const float* __restrict__ w,
                           const float* __restrict__ deg, float* __restrict__ dinv,
                           float* __restrict__ z, int N) {
    int wid  = (blockIdx.x * blockDim.x + threadIdx.x) >> 6;
    int lane = threadIdx.x & 63;
    if (wid >= N) return;
    const float2* xr = reinterpret_cast<const float2*>(x + (size_t)wid * FEAT);
    const float2* wr = reinterpret_cast<const float2*>(w);
    float2 xv = xr[lane];
    float2 wv = wr[lane];
    float s = xv.x * wv.x + xv.y * wv.y;
    #pragma unroll
    for (int o = 32; o >= 1; o >>= 1) s += __shfl_xor(s, o, 64);
    if (lane == 0) { z[wid] = s; dinv[wid] = 1.0f / sqrtf(deg[wid]); }
}
__global__ void f_hop_self(const float* __restrict__ za, const float* __restrict__ dinv,
                           float* __restrict__ zb, int N) {
    int i = blockIdx.x * blockDim.x + threadIdx.x;
    if (i < N) { float d = dinv[i]; zb[i] = d * d * za[i]; }
}
__global__ void f_hop_edges(const int* __restrict__ src, const int* __restrict__ dst,
                            const float* __restrict__ za, const float* __restrict__ dinv,
                            float* __restrict__ zb, int E) {
    int e = blockIdx.x * blockDim.x + threadIdx.x;
    if (e < E) {
        int s = src[e], d = dst[e];
        unsafeAtomicAdd(&zb[d], dinv[s] * dinv[d] * za[s]);
    }
}
__global__ void f_final(const float* __restrict__ z, const float* __restrict__ bias,
                        float* __restrict__ out, int N) {
    int i = blockIdx.x * blockDim.x + threadIdx.x;
    if (i < N) { float v = z[i] + bias[0]; out[i] = v * v; }
}

// ---------------- launcher ----------------
extern "C" void kernel_launch(void* const* d_in, const int* in_sizes, int n_in,
                              void* d_out, int out_size, void* d_ws, size_t ws_size,
                              hipStream_t stream) {
    const float* x    = (const float*)d_in[0];
    const int*   ei   = (const int*)d_in[1];
    const float* w    = (const float*)d_in[2];
    const float* bias = (const float*)d_in[3];
    float*       out  = (float*)d_out;

    const int N = in_sizes[0] / FEAT;
    const int E = in_sizes[1] / 2;
    const int* src = ei;
    const int* dst = ei + E;

    const int NB   = (N + NPB - 1) / NPB;
    const int NGRP = (NB + GS - 1) >> GSH;

    // ws layout: ebuf | ebuf2 | z,u0,u1,u2 | gcnt | gflag | cnt2
    size_t ebuf_b  = (size_t)NB * NSCAT * CAPB * sizeof(unsigned);
    size_t ebuf2_b = (size_t)NB * CAP2 * sizeof(unsigned);
    size_t off_e2    = ebuf_b;
    size_t off_z     = off_e2 + ebuf2_b;
    size_t off_gcnt  = (off_z + (size_t)4 * N * sizeof(float) + 255) & ~(size_t)255;
    size_t off_gflag = off_gcnt + (size_t)NGRP * LINE * sizeof(int);
    size_t off_cnt2  = off_gflag + (size_t)NGRP * LINE * sizeof(int);
    size_t need      = off_cnt2 + (size_t)NB * NSCAT + 256;

    // co-residency: launch_bounds(256,2) -> 2 blocks/CU -> capacity 512 >= NB
    bool fast = (NB <= 512) && (NGRP <= LINE * 2) && (N <= (1 << SBITS)) &&
                ((size_t)E <= (size_t)8 * NB * NSCAT) &&     // cell mean <= CAPB/4
                ((size_t)E * 2 <= (size_t)NB * CAP2) &&      // bucket mean <= CAP2/2
                (ws_size >= need);

    if (fast) {
        unsigned*      ebuf  = (unsigned*)d_ws;
        unsigned*      ebuf2 = (unsigned*)((char*)d_ws + off_e2);
        float*         z     = (float*)((char*)d_ws + off_z);
        float*         u0    = z + N;
        float*         u1    = u0 + N;
        float*         u2    = u1 + N;
        int*           gcnt  = (int*)((char*)d_ws + off_gcnt);
        int*           gflag = (int*)((char*)d_ws + off_gflag);
        unsigned char* cnt2  = (unsigned char*)((char*)d_ws + off_cnt2);

        const int chunk = (E + NSCAT - 1) / NSCAT;

        k1_scat_gemv<<<NSCAT + NGEMV, TPB, 0, stream>>>(x, src, dst, w, N, E, NB, NGRP,
                                                        chunk, ebuf, cnt2, z,
                                                        gcnt, gflag);
        k2_fused<<<NB, TPB, 0, stream>>>(ebuf, cnt2, z, bias, ebuf2,
                                         u0, u1, u2, out, gcnt, gflag, N, NB, NGRP);
    } else {
        float* deg  = (float*)d_ws;
        float* dinv = deg;
        float* z0   = deg + N;
        float* z1   = z0 + N;
        const int B = 256;
        const int gN = (N + B - 1) / B;
        const int gE = (E + B - 1) / B;
        const int gW = (N * 64 + B - 1) / B;
        f_init_deg<<<gN, B, 0, stream>>>(deg, N);
        f_count_deg<<<gE, B, 0, stream>>>(dst, deg, E);
        f_dot_dinv<<<gW, B, 0, stream>>>(x, w, deg, dinv, z0, N);
        f_hop_self<<<gN, B, 0, stream>>>(z0, dinv, z1, N);
        f_hop_edges<<<gE, B, 0, stream>>>(src, dst, z0, dinv, z1, E);
        f_hop_self<<<gN, B, 0, stream>>>(z1, dinv, z0, N);
        f_hop_edges<<<gE, B, 0, stream>>>(src, dst, z1, dinv, z0, E);
        f_hop_self<<<gN, B, 0, stream>>>(z0, dinv, z1, N);
        f_hop_edges<<<gE, B, 0, stream>>>(src, dst, z0, dinv, z1, E);
        f_final<<<gN, B, 0, stream>>>(z1, bias, out, N);
    }
}